// Round 1
// 307.676 us; speedup vs baseline: 1.0341x; 1.0341x over previous
//
#include <hip/hip_runtime.h>
#include <stdint.h>

// out = x @ tanh(block_diag(blocks)) -- 16 blocks of 256x256. ALL BUFFERS FLOAT32.
// Kernel 1: tanh_pack -> wsT in CHUNKED+SWIZZLED bf16 layout, per block j (128 KB):
//   byte(n,k) = (k>>6)*32768 + n*128 + ((2*(k&63)) ^ ((n&7)<<4))
// Kernel 2: bdgemm2 -- one 512-thread WG per (mg,j), grid 16x16 = 256 WGs = 1/CU.
//   B block fully LDS-resident (128 KB, staged once via global_load_lds, swizzle
//   pre-applied in DRAM so linear DMA == swizzled LDS). A direct global->reg with
//   2-chunk prefetch; 4 counted-vmcnt barriers total, then barrier-free.

typedef float floatx4 __attribute__((ext_vector_type(4)));
typedef __bf16 bf16x8 __attribute__((ext_vector_type(8)));

#define LDX 4096
#define NBLK 16
#define BS 256

__device__ __forceinline__ unsigned int f2bf(float f) {
  union { float f; unsigned int i; } x;
  x.f = f;
  unsigned int r = x.i + 0x7FFFu + ((x.i >> 16) & 1u);  // RNE
  return r >> 16;
}

__device__ __forceinline__ bf16x8 pack8(const float4& a, const float4& b) {
  union { uint4 u; bf16x8 h; } v;
  v.u.x = f2bf(a.x) | (f2bf(a.y) << 16);
  v.u.y = f2bf(a.z) | (f2bf(a.w) << 16);
  v.u.z = f2bf(b.x) | (f2bf(b.y) << 16);
  v.u.w = f2bf(b.z) | (f2bf(b.w) << 16);
  return v.h;
}

// async global->LDS, 16B/lane. LDS dest = wave-uniform base + lane*16 in lane order.
__device__ __forceinline__ void async_copy16(const void* g, void* l) {
  __builtin_amdgcn_global_load_lds(
      (__attribute__((address_space(1))) void*)(uintptr_t)g,
      (__attribute__((address_space(3))) void*)(unsigned int)(uintptr_t)l,
      16, 0, 0);
}

// counted-vmcnt barrier: stage loads for the needed chunk are guaranteed retired
// when <= N vm-ops are outstanding (vmcnt retires in issue order; N = #vm-ops
// issued after that chunk's last stage instruction in program order).
#define BWAIT(N)                                              \
  do {                                                        \
    asm volatile("s_waitcnt vmcnt(" #N ")" ::: "memory");     \
    __builtin_amdgcn_s_barrier();                             \
    __builtin_amdgcn_sched_barrier(0);                        \
  } while (0)

// wsT: per j, chunked (k/64) rows of 128B with XOR-swizzled k-position.
__global__ __launch_bounds__(256) void tanh_pack(const float* __restrict__ blocks,
                                                 unsigned short* __restrict__ wsT) {
  __shared__ float tile[64][65];  // [k][n], +1 pad for conflict-free column reads
  const int t = threadIdx.x;
  const int tc = blockIdx.x, tr = blockIdx.y, j = blockIdx.z;
  const float* src = blocks + (size_t)(j * BS + tr * 64) * LDX + j * BS + tc * 64;
#pragma unroll
  for (int it = 0; it < 8; ++it) {
    int v = it * 256 + t;
    int row = v >> 5;       // k within tile, 0..63
    int c2 = (v & 31) * 2;  // n within tile, even
    float2 f = *(const float2*)(src + (size_t)row * LDX + c2);
    tile[row][c2] = tanhf(f.x);
    tile[row][c2 + 1] = tanhf(f.y);
  }
  __syncthreads();
  // chunk index == tr (64 k per chunk). Write swizzled dwords (pair k2,k2+1).
  unsigned char* dstj =
      (unsigned char*)wsT + (size_t)j * 131072 + (size_t)tr * 32768;
#pragma unroll
  for (int it = 0; it < 8; ++it) {
    int v = it * 256 + t;
    int nn = v >> 5;        // n within tile
    int k2 = (v & 31) * 2;  // k-local within chunk, even
    int n = tc * 64 + nn;   // 0..255
    unsigned int pair = f2bf(tile[k2][nn]) | (f2bf(tile[k2 + 1][nn]) << 16);
    unsigned int off = (unsigned)n * 128 + (((unsigned)(k2 * 2)) ^ (((unsigned)(n & 7)) << 4));
    *(unsigned int*)(dstj + off) = pair;  // coalesced within each 128B row
  }
}

__global__ __launch_bounds__(512, 2) void bdgemm2(const float* __restrict__ x,
                                                  const unsigned short* __restrict__ wsT,
                                                  float* __restrict__ out) {
  __shared__ unsigned short Bs[65536];  // 128 KB: [chunk(4)][n(256)][k(64) swizzled]
  const int t = threadIdx.x;
  const int lane = t & 63;
  const int wave = t >> 6;
  const int mg = blockIdx.x;  // 0..15 -> 512 rows each
  const int j = blockIdx.y;   // 0..15

  const int fr = lane & 15;        // m-row / n-col within 16
  const int kq = lane >> 4;        // k subgroup (x8)
  const int sw = (fr & 7) << 4;    // LDS XOR swizzle for this lane's n
  const int ko0 = ((kq * 16) + 0) ^ sw;   // kt=0 byte offset within 128B row
  const int ko1 = ((kq * 16) + 64) ^ sw;  // kt=1

  // A: lane reads rows (base+fr, base+16+fr), 8 consecutive k at kq*8.
  const float* xg = x + (size_t)(mg * 512 + wave * 32 + fr) * LDX + j * BS + kq * 8;
  char* ldsb = (char*)Bs;

  float4 s0[8], s1[8];  // A staging: [kt*4 + mi*2 + half]
  floatx4 acc[2][16];

  // sc = mblk*4 + c: mblk = sc>>2 (rows +256), c = sc&3 (cols +c*64)
  auto issueA = [&](float4* s, int sc) {
#pragma unroll
    for (int kt = 0; kt < 2; ++kt)
#pragma unroll
      for (int mi = 0; mi < 2; ++mi) {
        const float* q = xg + (size_t)((sc >> 2) * 256 + mi * 16) * LDX +
                         (sc & 3) * 64 + kt * 32;
        s[kt * 4 + mi * 2 + 0] = *(const float4*)(q);
        s[kt * 4 + mi * 2 + 1] = *(const float4*)(q + 4);
      }
  };

  auto compute = [&](int c, const float4* s) {
#pragma unroll
    for (int kt = 0; kt < 2; ++kt) {
      bf16x8 af0 = pack8(s[kt * 4 + 0], s[kt * 4 + 1]);
      bf16x8 af1 = pack8(s[kt * 4 + 2], s[kt * 4 + 3]);
      const char* bkt = ldsb + c * 32768 + fr * 128 + (kt ? ko1 : ko0);
#pragma unroll
      for (int ni = 0; ni < 16; ++ni) {
        bf16x8 bf = *(const bf16x8*)(bkt + ni * 2048);
        acc[0][ni] = __builtin_amdgcn_mfma_f32_16x16x32_bf16(af0, bf, acc[0][ni], 0, 0, 0);
        acc[1][ni] = __builtin_amdgcn_mfma_f32_16x16x32_bf16(af1, bf, acc[1][ni], 0, 0, 0);
      }
    }
  };

  auto zacc = [&]() {
#pragma unroll
    for (int a = 0; a < 2; ++a)
#pragma unroll
      for (int b = 0; b < 16; ++b) acc[a][b] = (floatx4){0.f, 0.f, 0.f, 0.f};
  };

  auto store = [&](int mblk) {
    float* op = out + (size_t)(mg * 512 + mblk * 256 + wave * 32 + kq * 4) * LDX +
                j * BS + fr;
#pragma unroll
    for (int mi = 0; mi < 2; ++mi)
#pragma unroll
      for (int ni = 0; ni < 16; ++ni)
#pragma unroll
        for (int r = 0; r < 4; ++r)
          op[(size_t)(mi * 16 + r) * LDX + ni * 16] = acc[mi][ni][r];
  };

  // ---- prologue: A prefetch for sc0,sc1, then stage all of B (chunk-ascending) ----
  issueA(s0, 0);
  issueA(s1, 1);
  const char* wsj = (const char*)wsT + (size_t)j * 131072;
#pragma unroll
  for (int i = 0; i < 16; ++i)  // 4 instrs per chunk per thread, i/4 = chunk
    async_copy16(wsj + i * 8192 + t * 16, ldsb + i * 8192 + t * 16);

  // ---- mblk 0: progressive counted-vmcnt barriers (B chunks land in order) ----
  // N = vm-ops issued after chunk c's last stage op: 12/8/4/0 stages + A-issues.
  zacc();
  BWAIT(12); compute(0, s0); issueA(s0, 2);
  BWAIT(16); compute(1, s1); issueA(s1, 3);
  BWAIT(20); compute(2, s0); issueA(s0, 4);
  BWAIT(24); compute(3, s1); issueA(s1, 5);
  store(0);

  // ---- mblk 1: B fully resident, zero barriers ----
  zacc();
  compute(0, s0); issueA(s0, 6);
  compute(1, s1); issueA(s1, 7);
  compute(2, s0);
  compute(3, s1);
  store(1);
}

// Fallback (no workspace): B from raw f32 blocks with inline tanh.
template <int BSTR>
__global__ __launch_bounds__(256) void bdgemm_fused(const float* __restrict__ x,
                                                    const float* __restrict__ bg,
                                                    float* __restrict__ out) {
  __shared__ unsigned short As[64 * 32];
  __shared__ unsigned short Bsf[256 * BSTR];
  const int t = threadIdx.x;
  const int lane = t & 63;
  const int wave = t >> 6;
  const int mtile = blockIdx.x;
  const int j = blockIdx.y;
  const int m0 = mtile * 64;
  const float* xg = x + (size_t)m0 * LDX + j * BS;
  const int srow = t >> 2;
  const int scol = (t & 3) * 8;
  const int wn = wave * 64;
  const int fr = lane & 15;
  const int fq = (lane >> 4) * 8;

  floatx4 acc[4][4];
#pragma unroll
  for (int a = 0; a < 4; ++a)
#pragma unroll
    for (int b = 0; b < 4; ++b) acc[a][b] = (floatx4){0.f, 0.f, 0.f, 0.f};

  for (int kt = 0; kt < 8; ++kt) {
    const int k0 = kt * 32;
    const float* ap = xg + (size_t)srow * LDX + k0 + scol;
    float4 a0 = *(const float4*)(ap);
    float4 a1 = *(const float4*)(ap + 4);
    uint4 pk;
    pk.x = f2bf(a0.x) | (f2bf(a0.y) << 16);
    pk.y = f2bf(a0.z) | (f2bf(a0.w) << 16);
    pk.z = f2bf(a1.x) | (f2bf(a1.y) << 16);
    pk.w = f2bf(a1.z) | (f2bf(a1.w) << 16);
    *(uint4*)(As + t * 8) = pk;
#pragma unroll
    for (int i = 0; i < 32; ++i) {
      const int idx = i * 256 + t;
      const int kk = idx >> 8;
      const int nn = idx & 255;
      float v = tanhf(bg[(size_t)(j * BS + k0 + kk) * LDX + j * BS + nn]);
      Bsf[nn * BSTR + kk] = (unsigned short)f2bf(v);
    }
    __syncthreads();
    bf16x8 af[4], bfm[4];
#pragma unroll
    for (int i = 0; i < 4; ++i) {
      af[i] = *(const bf16x8*)(As + (i * 16 + fr) * 32 + fq);
      bfm[i] = *(const bf16x8*)(Bsf + (wn + i * 16 + fr) * BSTR + fq);
    }
#pragma unroll
    for (int mi = 0; mi < 4; ++mi)
#pragma unroll
      for (int ni = 0; ni < 4; ++ni)
        acc[mi][ni] =
            __builtin_amdgcn_mfma_f32_16x16x32_bf16(af[mi], bfm[ni], acc[mi][ni], 0, 0, 0);
    __syncthreads();
  }
  const int r0 = (lane >> 4) * 4;
  const int ocol = j * BS + wn + fr;
#pragma unroll
  for (int mi = 0; mi < 4; ++mi)
#pragma unroll
    for (int ni = 0; ni < 4; ++ni) {
      float* op = out + (size_t)(m0 + mi * 16 + r0) * LDX + ocol + ni * 16;
#pragma unroll
      for (int r = 0; r < 4; ++r) op[(size_t)r * LDX] = acc[mi][ni][r];
    }
}

extern "C" void kernel_launch(void* const* d_in, const int* in_sizes, int n_in,
                              void* d_out, int out_size, void* d_ws, size_t ws_size,
                              hipStream_t stream) {
  const float* x = (const float*)d_in[0];       // 8192x4096 f32
  const float* blocks = (const float*)d_in[1];  // 4096x4096 f32
  // d_in[2] (mask) unused: block structure is static, tanh(0)=0.
  float* out = (float*)d_out;

  const size_t need = (size_t)NBLK * BS * BS * sizeof(unsigned short);  // 2 MB
  if (d_ws != nullptr && ws_size >= need) {
    unsigned short* wsT = (unsigned short*)d_ws;
    tanh_pack<<<dim3(4, 4, NBLK), 256, 0, stream>>>(blocks, wsT);
    bdgemm2<<<dim3(16, NBLK), 512, 0, stream>>>(x, wsT, out);
  } else {
    bdgemm_fused<40><<<dim3(128, NBLK), 256, 0, stream>>>(x, blocks, out);
  }
}

// Round 4
// 298.143 us; speedup vs baseline: 1.0672x; 1.0320x over previous
//
#include <hip/hip_runtime.h>
#include <stdint.h>

// out = x @ tanh(block_diag(blocks)) -- 16 blocks of 256x256. ALL BUFFERS FLOAT32.
// Kernel 1: tanh_pack -> wsT in CHUNKED+SWIZZLED bf16 layout, per block j (128 KB):
//   byte(n,k) = (k>>6)*32768 + n*128 + ((2*(k&63)) ^ ((n&7)<<4))
// Kernel 2: bdgemm4 -- one 512-thread WG per (mg,j), grid 16x16. B fully LDS-resident
//   (128 KB). A streamed in 64-row strips: UNIFORM-ROW 1KB-contiguous global loads
//   (lane = column, one row per instruction) -> regs -> bf16 pack -> swizzled LDS,
//   with As split into two k-halves (16 KB buffer; LDS total 144 KB < 160 KB limit).
//   4 lgkm-only barriers per strip; vmcnt never drained in the loop.

typedef float floatx4 __attribute__((ext_vector_type(4)));
typedef __bf16 bf16x8 __attribute__((ext_vector_type(8)));

#define LDX 4096
#define NBLK 16
#define BS 256

__device__ __forceinline__ unsigned int f2bf(float f) {
  union { float f; unsigned int i; } x;
  x.f = f;
  unsigned int r = x.i + 0x7FFFu + ((x.i >> 16) & 1u);  // RNE
  return r >> 16;
}

// async global->LDS, 16B/lane. LDS dest = wave-uniform base + lane*16 in lane order.
__device__ __forceinline__ void async_copy16(const void* g, void* l) {
  __builtin_amdgcn_global_load_lds(
      (__attribute__((address_space(1))) void*)(uintptr_t)g,
      (__attribute__((address_space(3))) void*)(unsigned int)(uintptr_t)l,
      16, 0, 0);
}

// wsT: per j, chunked (k/64) rows of 128B with XOR-swizzled k-position.
__global__ __launch_bounds__(256) void tanh_pack(const float* __restrict__ blocks,
                                                 unsigned short* __restrict__ wsT) {
  __shared__ float tile[64][65];  // [k][n], +1 pad for conflict-free column reads
  const int t = threadIdx.x;
  const int tc = blockIdx.x, tr = blockIdx.y, j = blockIdx.z;
  const float* src = blocks + (size_t)(j * BS + tr * 64) * LDX + j * BS + tc * 64;
#pragma unroll
  for (int it = 0; it < 8; ++it) {
    int v = it * 256 + t;
    int row = v >> 5;       // k within tile, 0..63
    int c2 = (v & 31) * 2;  // n within tile, even
    float2 f = *(const float2*)(src + (size_t)row * LDX + c2);
    tile[row][c2] = tanhf(f.x);
    tile[row][c2 + 1] = tanhf(f.y);
  }
  __syncthreads();
  // chunk index == tr (64 k per chunk). Write swizzled dwords (pair k2,k2+1).
  unsigned char* dstj =
      (unsigned char*)wsT + (size_t)j * 131072 + (size_t)tr * 32768;
#pragma unroll
  for (int it = 0; it < 8; ++it) {
    int v = it * 256 + t;
    int nn = v >> 5;        // n within tile
    int k2 = (v & 31) * 2;  // k-local within chunk, even
    int n = tc * 64 + nn;   // 0..255
    unsigned int pair = f2bf(tile[k2][nn]) | (f2bf(tile[k2 + 1][nn]) << 16);
    unsigned int off = (unsigned)n * 128 + (((unsigned)(k2 * 2)) ^ (((unsigned)(n & 7)) << 4));
    *(unsigned int*)(dstj + off) = pair;  // coalesced within each 128B row
  }
}

__global__ __launch_bounds__(512) void bdgemm4(const float* __restrict__ x,
                                               const unsigned short* __restrict__ wsT,
                                               float* __restrict__ out) {
  __shared__ unsigned short Bs[65536];  // 128 KB: [chunk(4)][n(256)][k(64) swizzled]
  __shared__ unsigned short As[8192];   //  16 KB: [row(64)][k-half(128) swizzled]
  const int t = threadIdx.x;
  const int lane = t & 63;
  const int wave = t >> 6;  // 0..7 = wm(2) x wn(4)
  const int wm = wave >> 2;
  const int wn = wave & 3;
  const int mg = blockIdx.x;  // 0..15 -> 512 rows
  const int j = blockIdx.y;   // 0..15

  const int fr = lane & 15;      // m-row / n-col within 16
  const int kq = lane >> 4;      // k subgroup (x8)
  const int sw = (fr & 7) << 4;  // XOR swizzle (bits 4-6) for frag reads

  char* bsb = (char*)Bs;
  char* asb = (char*)As;

  // A global loads: lane = column. One row per instruction = 1KB contiguous burst.
  const float* xrow = x + (size_t)(mg * 512 + wave * 8) * LDX + j * BS + lane * 4;

  float4 ra[8], rb[8];  // two strips of reg-staged A (8 rows/wave, 16B/lane/row)
  floatx4 acc[2][4];

  auto loadA = [&](float4* r, int strip) {
#pragma unroll
    for (int q = 0; q < 8; ++q)
      r[q] = *(const float4*)(xrow + (size_t)(strip * 64 + q) * LDX);
  };

  // pack k-half h (lane holds bf16 k-bytes 8*lane..8*lane+7; half = lane>>5)
  auto packAh = [&](const float4* r, int h) {
    if ((lane >> 5) == h) {
      const int kb = 8 * (lane & 31);  // byte within 256B half-row
#pragma unroll
      for (int q = 0; q < 8; ++q) {
        const int lrow = wave * 8 + q;
        uint2 d;
        d.x = f2bf(r[q].x) | (f2bf(r[q].y) << 16);
        d.y = f2bf(r[q].z) | (f2bf(r[q].w) << 16);
        // writer XOR == reader XOR (bits 4-6), bijective within 256B row
        *(uint2*)(asb + lrow * 256 + (kb ^ ((lrow & 7) << 4))) = d;
      }
    }
  };

  auto barrier = [&]() {  // lgkm-only barrier: global loads/stores stay in flight
    asm volatile("s_waitcnt lgkmcnt(0)" ::: "memory");
    __builtin_amdgcn_s_barrier();
    __builtin_amdgcn_sched_barrier(0);
  };

  auto compute_half = [&](int h) {
#pragma unroll
    for (int kk2 = 0; kk2 < 4; ++kk2) {
      const int kk = h * 4 + kk2;                     // global k-chunk 0..7
      const int c = kk >> 1;                          // B chunk
      const int kb = (((kk & 1) * 64 + kq * 16) ^ sw);  // B k-byte in 128B row
      const int ka = ((kk2 * 64 + kq * 16) ^ sw);       // A k-byte in 256B half-row
      bf16x8 a0 = *(const bf16x8*)(asb + (wm * 32 + fr) * 256 + ka);
      bf16x8 a1 = *(const bf16x8*)(asb + (wm * 32 + 16 + fr) * 256 + ka);
      const char* bb = bsb + c * 32768 + (wn * 64 + fr) * 128 + kb;
#pragma unroll
      for (int ni = 0; ni < 4; ++ni) {
        bf16x8 bf = *(const bf16x8*)(bb + ni * 2048);
        acc[0][ni] = __builtin_amdgcn_mfma_f32_16x16x32_bf16(a0, bf, acc[0][ni], 0, 0, 0);
        acc[1][ni] = __builtin_amdgcn_mfma_f32_16x16x32_bf16(a1, bf, acc[1][ni], 0, 0, 0);
      }
    }
  };

  auto store = [&](int strip) {
    // C/D layout (m89-verified): col = lane&15, row = (lane>>4)*4 + reg
    float* op0 = out + (size_t)(mg * 512 + strip * 64 + wm * 32 + kq * 4) * LDX +
                 j * BS + wn * 64 + fr;
#pragma unroll
    for (int mi = 0; mi < 2; ++mi)
#pragma unroll
      for (int ni = 0; ni < 4; ++ni) {
        float* op = op0 + (size_t)(mi * 16) * LDX + ni * 16;
#pragma unroll
        for (int r = 0; r < 4; ++r) op[(size_t)r * LDX] = acc[mi][ni][r];
      }
  };

  // ---- prologue ----
  loadA(ra, 0);
  const char* wsj = (const char*)wsT + (size_t)j * 131072;
#pragma unroll
  for (int i = 0; i < 16; ++i)  // stage all of B (16 x 8KB, linear, pre-swizzled)
    async_copy16(wsj + i * 8192 + t * 16, bsb + i * 8192 + t * 16);
  loadA(rb, 1);
  packAh(ra, 0);  // compiler waits vmcnt for ra only (in-order; B+rb still out)
  asm volatile("s_waitcnt vmcnt(8)" ::: "memory");  // all B stages done (rb may fly)

  // ---- 8 strips of 64 rows, two k-halves each; strip s+2 prefetched mid-strip ----
#pragma unroll
  for (int s = 0; s < 8; ++s) {
    float4* cur = (s & 1) ? rb : ra;  // holds strip s
    float4* nxt = (s & 1) ? ra : rb;  // holds strip s+1
#pragma unroll
    for (int a = 0; a < 2; ++a)
#pragma unroll
      for (int b = 0; b < 4; ++b) acc[a][b] = (floatx4){0.f, 0.f, 0.f, 0.f};
    barrier();           // As h0 of strip s visible to all waves
    compute_half(0);
    barrier();           // h0 reads done
    packAh(cur, 1);      // overwrite As with h1 (reads cur regs, then cur is free)
    if (s + 2 < 8) loadA(cur, s + 2);
    barrier();           // h1 visible
    compute_half(1);
    store(s);            // stores stay in flight; no vmcnt drain
    if (s < 7) {
      barrier();         // h1 reads done
      packAh(nxt, 0);    // pack h0 of strip s+1 from the other buffer
    }
  }
}

// Fallback (no workspace): B from raw f32 blocks with inline tanh.
template <int BSTR>
__global__ __launch_bounds__(256) void bdgemm_fused(const float* __restrict__ x,
                                                    const float* __restrict__ bg,
                                                    float* __restrict__ out) {
  __shared__ unsigned short As[64 * 32];
  __shared__ unsigned short Bsf[256 * BSTR];
  const int t = threadIdx.x;
  const int lane = t & 63;
  const int wave = t >> 6;
  const int mtile = blockIdx.x;
  const int j = blockIdx.y;
  const int m0 = mtile * 64;
  const float* xg = x + (size_t)m0 * LDX + j * BS;
  const int srow = t >> 2;
  const int scol = (t & 3) * 8;
  const int wn = wave * 64;
  const int fr = lane & 15;
  const int fq = (lane >> 4) * 8;

  floatx4 acc[4][4];
#pragma unroll
  for (int a = 0; a < 4; ++a)
#pragma unroll
    for (int b = 0; b < 4; ++b) acc[a][b] = (floatx4){0.f, 0.f, 0.f, 0.f};

  for (int kt = 0; kt < 8; ++kt) {
    const int k0 = kt * 32;
    const float* ap = xg + (size_t)srow * LDX + k0 + scol;
    float4 a0 = *(const float4*)(ap);
    float4 a1 = *(const float4*)(ap + 4);
    uint4 pk;
    pk.x = f2bf(a0.x) | (f2bf(a0.y) << 16);
    pk.y = f2bf(a0.z) | (f2bf(a0.w) << 16);
    pk.z = f2bf(a1.x) | (f2bf(a1.y) << 16);
    pk.w = f2bf(a1.z) | (f2bf(a1.w) << 16);
    *(uint4*)(As + t * 8) = pk;
#pragma unroll
    for (int i = 0; i < 32; ++i) {
      const int idx = i * 256 + t;
      const int kk = idx >> 8;
      const int nn = idx & 255;
      float v = tanhf(bg[(size_t)(j * BS + k0 + kk) * LDX + j * BS + nn]);
      Bsf[nn * BSTR + kk] = (unsigned short)f2bf(v);
    }
    __syncthreads();
    bf16x8 af[4], bfm[4];
#pragma unroll
    for (int i = 0; i < 4; ++i) {
      af[i] = *(const bf16x8*)(As + (i * 16 + fr) * 32 + fq);
      bfm[i] = *(const bf16x8*)(Bsf + (wn + i * 16 + fr) * BSTR + fq);
    }
#pragma unroll
    for (int mi = 0; mi < 4; ++mi)
#pragma unroll
      for (int ni = 0; ni < 4; ++ni)
        acc[mi][ni] =
            __builtin_amdgcn_mfma_f32_16x16x32_bf16(af[mi], bfm[ni], acc[mi][ni], 0, 0, 0);
    __syncthreads();
  }
  const int r0 = (lane >> 4) * 4;
  const int ocol = j * BS + wn + fr;
#pragma unroll
  for (int mi = 0; mi < 4; ++mi)
#pragma unroll
    for (int ni = 0; ni < 4; ++ni) {
      float* op = out + (size_t)(m0 + mi * 16 + r0) * LDX + ocol + ni * 16;
#pragma unroll
      for (int r = 0; r < 4; ++r) op[(size_t)r * LDX] = acc[mi][ni][r];
    }
}

extern "C" void kernel_launch(void* const* d_in, const int* in_sizes, int n_in,
                              void* d_out, int out_size, void* d_ws, size_t ws_size,
                              hipStream_t stream) {
  const float* x = (const float*)d_in[0];       // 8192x4096 f32
  const float* blocks = (const float*)d_in[1];  // 4096x4096 f32
  // d_in[2] (mask) unused: block structure is static, tanh(0)=0.
  float* out = (float*)d_out;

  const size_t need = (size_t)NBLK * BS * BS * sizeof(unsigned short);  // 2 MB
  if (d_ws != nullptr && ws_size >= need) {
    unsigned short* wsT = (unsigned short*)d_ws;
    tanh_pack<<<dim3(4, 4, NBLK), 256, 0, stream>>>(blocks, wsT);
    bdgemm4<<<dim3(16, NBLK), 512, 0, stream>>>(x, wsT, out);
  } else {
    bdgemm_fused<40><<<dim3(128, NBLK), 256, 0, stream>>>(x, blocks, out);
  }
}